// Round 1
// baseline (501.582 us; speedup 1.0000x reference)
//
#include <hip/hip_runtime.h>
#include <hip/hip_bf16.h>

#define T_STEPS 2048
#define BATCH 16
#define DIM 1024
#define NDIM 64
#define M_TOTAL (T_STEPS * BATCH)  // 32768
#define STRIDE (BATCH * NDIM)      // floats per timestep in Kp/Qp = 1024
#define CH 32                      // recurrence chunk (timesteps per LDS buffer)

typedef __attribute__((ext_vector_type(8))) short bf16x8;
typedef __attribute__((ext_vector_type(4))) float f32x4;
typedef __attribute__((ext_vector_type(2))) float f32x2;

#define NEG_LOG2E -1.44269504088896f

__device__ inline unsigned pk_bf(float lo, float hi) {
    __hip_bfloat162 h = __float22bfloat162_rn(float2{lo, hi});
    return *(unsigned*)&h;  // v_cvt_pk_bf16_f32
}

template <int CTRL>
__device__ inline float dpp_add(float x) {
    int v = __builtin_amdgcn_update_dpp(0, __float_as_int(x), CTRL, 0xF, 0xF, true);
    return x + __int_as_float(v);
}
// full sum across contiguous 16-lane rows (result in all 16 lanes)
__device__ inline float red16(float x) {
    x = dpp_add<0xB1>(x);   // quad_perm xor1
    x = dpp_add<0x4E>(x);   // quad_perm xor2
    x = dpp_add<0x141>(x);  // row_half_mirror (xor4)
    x = dpp_add<0x140>(x);  // row_mirror (xor8)
    return x;
}
__device__ inline float fast_sigmoid(float z) {
    return __builtin_amdgcn_rcpf(1.f + __expf(-z));
}

#define AS1 __attribute__((address_space(1)))
#define AS3 __attribute__((address_space(3)))
__device__ inline void gl_lds16(const float* g, float* l) {
    __builtin_amdgcn_global_load_lds((const AS1 unsigned*)g, (AS3 unsigned*)l, 16, 0, 0);
}
__device__ inline void gl_lds16s(const unsigned short* g, unsigned short* l) {
    __builtin_amdgcn_global_load_lds((const AS1 unsigned*)g, (AS3 unsigned*)l, 16, 0, 0);
}
__device__ inline void gl_lds4(const float* g, float* l) {
    __builtin_amdgcn_global_load_lds((const AS1 unsigned*)g, (AS3 unsigned*)l, 4, 0, 0);
}
#define WAIT_VM0 do { __builtin_amdgcn_s_waitcnt(0x0F70); asm volatile("" ::: "memory"); } while (0)

// ---------------- W prepack: fp32 -> bf16, row order [K, Q, V, A] ----------------
__global__ __launch_bounds__(256) void pack_w(
    const float* __restrict__ Wk, const float* __restrict__ Wq,
    const float* __restrict__ Wv, const float* __restrict__ Wa,
    unsigned short* __restrict__ Wb) {
    int n = blockIdx.x;  // 0..255
    int sel = n >> 6;
    const float* W = (sel == 0) ? Wk : (sel == 1) ? Wq : (sel == 2) ? Wv : Wa;
    int k4 = threadIdx.x * 4;
    float4 f = *(const float4*)(W + (size_t)(n & 63) * DIM + k4);
    uint2 u;
    u.x = pk_bf(f.x, f.y);
    u.y = pk_bf(f.z, f.w);
    *(uint2*)(Wb + (size_t)n * DIM + k4) = u;
}

// ---------------- projection: m97-style 128x128 tile, global_load_lds staging ----------------
// grid (256 m-tiles, 2 n-tiles) x 256 threads = 512 blocks (2/CU). BK=64, 16 k-iters.
// A staged fp32 (converted at frag build), B staged pre-packed bf16.
// n-tile0 = [K|Q], n-tile1 = [V|A]; V/A written interleaved to VAi.
// A-lane values are the alpha LOGIT pre-scaled by -log2e (b_alpha folded in), so the
// recurrence can use exp2 directly: sigmoid(z) = rcp(1 + exp2(-z*log2e)).
__global__ __launch_bounds__(256, 2) void proj_kernel(
    const float* __restrict__ x, const unsigned short* __restrict__ Wb,
    const float* __restrict__ ba, float* __restrict__ Kp, float* __restrict__ Qp,
    float* __restrict__ VAi) {
    __shared__ float sA[128 * 64];            // 32 KB fp32
    __shared__ unsigned short sB[128 * 64];   // 16 KB bf16

    const int m0 = blockIdx.x * 128;
    const int ntile = blockIdx.y;
    const int tid = threadIdx.x;
    const int wv = tid >> 6, lane = tid & 63, lrow = lane & 15, quad = lane >> 4;
    const int wm = wv & 1, wn = wv >> 1;   // wave = (m-half, n-half) of 128x128 tile

    f32x4 acc[4][4];
#pragma unroll
    for (int a = 0; a < 4; a++)
#pragma unroll
        for (int b = 0; b < 4; b++) acc[a][b] = (f32x4)(0.f);

    // staging bases: lane-contiguous LDS dest (wave-uniform base + lane*16)
    const float* xg = x + (size_t)(m0 + (tid >> 4)) * DIM + (tid & 15) * 4;
    const unsigned short* wg = Wb + (size_t)(ntile * 128 + (tid >> 3)) * DIM + (tid & 7) * 8;

    for (int it = 0; it < 16; ++it) {
        const int k0 = it * 64;
        __syncthreads();  // previous iteration's frag reads done
#pragma unroll
        for (int j = 0; j < 8; ++j)  // A: 128x64 fp32 = 32 KB
            gl_lds16(xg + (size_t)(16 * j) * DIM + k0, &sA[(tid + 256 * j) * 4]);
#pragma unroll
        for (int j = 0; j < 4; ++j)  // B: 128x64 bf16 = 16 KB
            gl_lds16s(wg + (size_t)(32 * j) * DIM + k0, &sB[(tid + 256 * j) * 8]);
        WAIT_VM0;
        __syncthreads();

#pragma unroll
        for (int ks = 0; ks < 2; ++ks) {
            bf16x8 af[4];
#pragma unroll
            for (int mt = 0; mt < 4; ++mt) {
                const float* pa = &sA[(wm * 64 + mt * 16 + lrow) * 64 + ks * 32 + quad * 8];
                float4 lo = ((const float4*)pa)[0], hi = ((const float4*)pa)[1];
                unsigned pk[4] = {pk_bf(lo.x, lo.y), pk_bf(lo.z, lo.w),
                                  pk_bf(hi.x, hi.y), pk_bf(hi.z, hi.w)};
                af[mt] = *(bf16x8*)pk;
            }
#pragma unroll
            for (int nt = 0; nt < 4; ++nt) {
                bf16x8 bfr = *(const bf16x8*)&sB[(wn * 64 + nt * 16 + lrow) * 64 + ks * 32 + quad * 8];
#pragma unroll
                for (int mt = 0; mt < 4; ++mt)
                    acc[mt][nt] = __builtin_amdgcn_mfma_f32_16x16x32_bf16(af[mt], bfr, acc[mt][nt], 0, 0, 0);
            }
        }
    }

    // epilogue: C/D layout col = lane&15, row = quad*4 + reg  [m89-verified]
    const int g2 = ntile * 2 + wn;  // 0=K 1=Q 2=V 3=A
    float bav[4];
    if (g2 == 3) {
#pragma unroll
        for (int nt = 0; nt < 4; ++nt) bav[nt] = ba[nt * 16 + lrow];
    }
#pragma unroll
    for (int mt = 0; mt < 4; ++mt)
#pragma unroll
        for (int nt = 0; nt < 4; ++nt) {
            int col = nt * 16 + lrow;
#pragma unroll
            for (int reg = 0; reg < 4; ++reg) {
                int m = m0 + wm * 64 + mt * 16 + quad * 4 + reg;
                float vvv = acc[mt][nt][reg];
                if (g2 == 0) Kp[(size_t)m * 64 + col] = vvv;
                else if (g2 == 1) Qp[(size_t)m * 64 + col] = vvv;
                else if (g2 == 2) VAi[(size_t)m * 128 + col * 2] = vvv;
                else VAi[(size_t)m * 128 + col * 2 + 1] = NEG_LOG2E * (vvv + bav[nt]);
            }
        }
}

// ---------------- kq[m] = K[m,:].Q[m,:]   kk[m] = K[m,:].K[m+B,:]  (k_t . k_{t+1}) ----------------
__global__ __launch_bounds__(256) void kq_kernel(
    const float* __restrict__ Kp, const float* __restrict__ Qp,
    float* __restrict__ kq, float* __restrict__ kk) {
    int m = blockIdx.x * 16 + (threadIdx.x >> 4);
    int c = threadIdx.x & 15;
    float4 k = *(const float4*)(Kp + (size_t)m * 64 + c * 4);
    float4 q = *(const float4*)(Qp + (size_t)m * 64 + c * 4);
    float4 kn = {0.f, 0.f, 0.f, 0.f};
    if (m + BATCH < M_TOTAL) kn = *(const float4*)(Kp + (size_t)(m + BATCH) * 64 + c * 4);
    float pq = k.x * q.x + k.y * q.y + k.z * q.z + k.w * q.w;
    float pk = k.x * kn.x + k.y * kn.y + k.z * kn.z + k.w * kn.w;
    pq = red16(pq);
    pk = red16(pk);
    if (c == 0) { kq[m] = pq; kk[m] = pk; }
}

// ---------------- recurrence ----------------
// grid (16 row-groups, 16 batches) x 64; lane = r*16+c; row i = g*4+r, cols c*4..+3
//
// One-step look-ahead (exact algebra) takes the matvec+reduction OFF the serial chain:
//   rk_{t+1} = S_t.k_{t+1} = alpha_t*(S_{t-1}.k_{t+1}) + (1-alpha_t)*v_t*(k_t.k_{t+1})
//            = fma(alpha_t, crossk_t - v*kk_t, v*kk_t)
// crossk_t = S_{t-1}.k_{t+1} only needs the PREVIOUS state -> 2-step slack for the
// matvec + red16. Serial chain per step: fma -> exp2 -> add -> rcp -> fma (~5 ops).
__global__ __launch_bounds__(64, 1) void recur_kernel(
    const float* __restrict__ Kp, const float* __restrict__ Qp,
    const float* __restrict__ VAi, const float* __restrict__ KQp,
    const float* __restrict__ KKp,
    const float* __restrict__ S0, const float* __restrict__ d_alpha,
    float* __restrict__ out, float* __restrict__ Sout) {
    __shared__ float Kl[2][CH][64];   // 16 KB
    __shared__ float Ql[2][CH][64];   // 16 KB
    __shared__ float VAl[2][CH][8];   // 2 KB: [t] = v0,a0,v1,a1,v2,a2,v3,a3 (rows g*4..+3)
    __shared__ float KQl[2][64];      // 0.5 KB (only [0..31] used)
    __shared__ float KKl[2][64];      // 0.5 KB
    __shared__ float Ol[CH][4];       // per-chunk output staging

    int b = blockIdx.y, g = blockIdx.x, lane = threadIdx.x;
    int r = lane >> 4, c = lane & 15, i = g * 4 + r, c4 = c * 4;

    float4 sv = *(const float4*)(S0 + ((size_t)b * NDIM + i) * NDIM + c4);
    f32x2 s01 = {sv.x, sv.y}, s23 = {sv.z, sv.w};
    float da2 = d_alpha[i] * NEG_LOG2E;  // alpha logit pre-scaled for exp2 form

    const float* Kbase = Kp + (size_t)b * NDIM + (size_t)(lane >> 4) * STRIDE + (lane & 15) * 4;
    const float* Qbase = Qp + (size_t)b * NDIM + (size_t)(lane >> 4) * STRIDE + (lane & 15) * 4;
    const float* VAbase = VAi + (size_t)b * 128 + g * 8 + (lane & 1) * 4 + (size_t)(lane >> 1) * 2048;
    const float* KQbase = KQp + b + (size_t)(lane & 31) * BATCH;
    const float* KKbase = KKp + b + (size_t)(lane & 31) * BATCH;
    const float* Kgl = Kp + (size_t)b * NDIM + c4;  // per-lane column of k row (for boundary k)

    auto load_chunk = [&](int t0, int buf) {
#pragma unroll
        for (int j = 0; j < 8; ++j) {
            gl_lds16(Kbase + (size_t)(t0 + j * 4) * STRIDE, &Kl[buf][j * 4][0]);
            gl_lds16(Qbase + (size_t)(t0 + j * 4) * STRIDE, &Ql[buf][j * 4][0]);
        }
        gl_lds16(VAbase + (size_t)t0 * 2048, &VAl[buf][0][0]);
        gl_lds4(KQbase + (size_t)t0 * BATCH, &KQl[buf][0]);
        gl_lds4(KKbase + (size_t)t0 * BATCH, &KKl[buf][0]);
    };

    load_chunk(0, 0);
    WAIT_VM0;

    // register pipeline: slot sl=tl&1 holds (q,va,kq,kk) for local step tl and k for tl+1.
    // kc = k_t carried by shifting the consumed k_{t+1}.
    f32x2 kc01, kc23, kn01[2], kn23[2], q01[2], q23[2], va[2];
    float kqv[2], kkv[2], rk;
    {
        const float* Kb0 = &Kl[0][0][0];
        const float* Qb0 = &Ql[0][0][0];
        f32x4 k0 = *(const f32x4*)(Kb0 + c4);
        kc01 = k0.lo; kc23 = k0.hi;
#pragma unroll
        for (int u = 0; u < 2; ++u) {
            f32x4 kk_ = *(const f32x4*)(Kb0 + (u + 1) * 64 + c4);
            kn01[u] = kk_.lo; kn23[u] = kk_.hi;
            f32x4 qq = *(const f32x4*)(Qb0 + u * 64 + c4);
            q01[u] = qq.lo; q23[u] = qq.hi;
            va[u] = *(const f32x2*)&VAl[0][u][r * 2];
            kqv[u] = KQl[0][u];
            kkv[u] = KKl[0][u];
        }
        // rk_0 = S0_row . k_0
        f32x2 p = kc01 * s01;
        p = kc23 * s23 + p;
        rk = red16(p.x + p.y);
    }

    for (int j = 0; j < T_STEPS / CH; ++j) {
        int cb = j & 1;
        if (j + 1 < T_STEPS / CH) load_chunk((j + 1) * CH, cb ^ 1);
        // boundary k: local CH == next chunk's local 0, straight to regs (global,
        // arrives long before its use at tl=CH-3). For the last chunk this reads the
        // start of Qp (in-workspace, finite) and the result is never consumed.
        f32x4 kb = *(const f32x4*)(Kgl + (size_t)((j + 1) * CH) * STRIDE);

        const float* Kb = &Kl[cb][0][0];
        const float* Qb = &Ql[cb][0][0];
        const float* Vb = &VAl[cb][0][0];
        const float* Qk = &KQl[cb][0];
        const float* Kk = &KKl[cb][0];

#pragma unroll
        for (int tl = 0; tl < CH; ++tl) {
            int sl = tl & 1;
            f32x2 knA = kn01[sl], knB = kn23[sl];   // k_{t+1}
            f32x2 q0v = q01[sl], q1v = q23[sl];
            f32x2 vva = va[sl];
            float kqs = kqv[sl], kks = kkv[sl];
            if (tl < CH - 2) {
                f32x4 qq = *(const f32x4*)(Qb + (tl + 2) * 64 + c4);
                q01[sl] = qq.lo; q23[sl] = qq.hi;
                va[sl] = *(const f32x2*)&Vb[(tl + 2) * 8 + r * 2];
                kqv[sl] = Qk[tl + 2];
                kkv[sl] = Kk[tl + 2];
            }
            if (tl < CH - 3) {                       // k pipeline shifted +1
                f32x4 kk_ = *(const f32x4*)(Kb + (tl + 3) * 64 + c4);
                kn01[sl] = kk_.lo; kn23[sl] = kk_.hi;
            } else if (tl == CH - 3) {
                kn01[sl] = kb.lo; kn23[sl] = kb.hi;  // local CH = next chunk's k_0
            }

            // matvecs against s_{t-1} — off the alpha chain (2-step slack)
            f32x2 pq_ = q0v * s01; pq_ = q1v * s23 + pq_;
            f32x2 pk_ = knA * s01; pk_ = knB * s23 + pk_;
            float rq = red16(pq_.x + pq_.y);   // s_{t-1}.q_t
            float ck = red16(pk_.x + pk_.y);   // crossk_t = s_{t-1}.k_{t+1}

            float v = vva.x;
            f32x2 w01 = v * kc01, w23 = v * kc23;       // pre-alpha
            f32x2 d01 = s01 - w01, d23 = s23 - w23;     // pre-alpha
            float vkk = v * kks, vkq = v * kqs;
            float ckm = ck - vkk, rqm = rq - vkq;

            // serial chain: rk -> alpha -> rk'
            float alpha = __builtin_amdgcn_rcpf(1.f + __builtin_amdgcn_exp2f(fmaf(da2, rk, vva.y)));
            rk = fmaf(alpha, ckm, vkk);   // rk_{t+1}

            f32x2 a2 = {alpha, alpha};
            s01 = w01 + a2 * d01;   // s = w + alpha*(s-w)
            s23 = w23 + a2 * d23;

            float o = fmaf(alpha, rqm, vkq);   // S_t.q_t = alpha*(rq-v*kq) + v*kq
            float ov = o * o * fast_sigmoid(o);
            if (c == 0) Ol[tl][r] = ov;
            kc01 = knA; kc23 = knB;            // k_{t+1} becomes next step's k_t
        }
        WAIT_VM0;  // chunk j+1 staged long ago; also retires old output stores

        if (lane < 32) {  // dump chunk outputs: lane = local t, 4 rows as float4
            float4 t4 = *(const float4*)&Ol[lane][0];
            *(float4*)(out + ((size_t)(j * CH + lane) * BATCH + b) * NDIM + g * 4) = t4;
        }

        if (j + 1 < T_STEPS / CH) {  // preload pipeline for next chunk
            int nb = cb ^ 1;
            const float* Kn = &Kl[nb][0][0];
            const float* Qn = &Ql[nb][0][0];
#pragma unroll
            for (int u = 0; u < 2; ++u) {
                f32x4 kk_ = *(const f32x4*)(Kn + (u + 1) * 64 + c4);
                kn01[u] = kk_.lo; kn23[u] = kk_.hi;
                f32x4 qq = *(const f32x4*)(Qn + u * 64 + c4);
                q01[u] = qq.lo; q23[u] = qq.hi;
                va[u] = *(const f32x2*)&VAl[nb][u][r * 2];
                kqv[u] = KQl[nb][u];
                kkv[u] = KKl[nb][u];
            }
            // kc for next chunk's tl=0 is kb, already shifted in at tl=CH-1
        }
    }

    float* so = Sout + ((size_t)b * NDIM + i) * NDIM + c4;
    *(float4*)so = float4{s01.x, s01.y, s23.x, s23.y};
}

extern "C" void kernel_launch(void* const* d_in, const int* in_sizes, int n_in,
                              void* d_out, int out_size, void* d_ws, size_t ws_size,
                              hipStream_t stream) {
    const float* x  = (const float*)d_in[0];
    const float* S0 = (const float*)d_in[1];
    const float* Wk = (const float*)d_in[2];
    const float* Wv = (const float*)d_in[3];
    const float* Wq = (const float*)d_in[4];
    const float* Wa = (const float*)d_in[5];
    const float* da = (const float*)d_in[6];
    const float* ba = (const float*)d_in[7];

    float* out = (float*)d_out;
    float* Sout = out + (size_t)T_STEPS * BATCH * NDIM;

    const size_t per = (size_t)M_TOTAL * NDIM;
    float* Kp  = (float*)d_ws;           // per floats
    float* Qp  = Kp + per;               // per
    float* VAi = Qp + per;               // 2*per (v,a interleaved per row)
    float* kq  = VAi + 2 * per;          // M_TOTAL
    float* kk  = kq + M_TOTAL;           // M_TOTAL (k_t . k_{t+1})
    unsigned short* Wb = (unsigned short*)(kk + M_TOTAL);  // 512 KB bf16

    pack_w<<<dim3(256), dim3(256), 0, stream>>>(Wk, Wq, Wv, Wa, Wb);
    proj_kernel<<<dim3(M_TOTAL / 128, 2), dim3(256), 0, stream>>>(x, Wb, ba, Kp, Qp, VAi);
    kq_kernel<<<dim3(M_TOTAL / 16), dim3(256), 0, stream>>>(Kp, Qp, kq, kk);
    recur_kernel<<<dim3(16, BATCH), dim3(64), 0, stream>>>(Kp, Qp, VAi, kq, kk, S0, da, out, Sout);
}